// Round 7
// baseline (359.219 us; speedup 1.0000x reference)
//
#include <hip/hip_runtime.h>
#include <hip/hip_bf16.h>

// B=8, N=2048, DIN=256, DOUT=256
// Ne = H@W ; M1 = G@Ne ; M2 = G^T@Ne
// out[:,0:256]   = relu(0.5*(M1+M2))
// out[:,256:512] = relu(G^T @ (M1 * inv_rs))
// out[:,512:768] = relu(G   @ (M2 * inv_cs))
//
// R15: roster trim. R6 (flip) won 15us but added cvt_h + out0k dispatches.
// This round: (1) gemmNE reads H fp32 directly (R4-verified A_F32ROW path),
// cvt_h deleted; (2) out0k folded into gemmF<1> h=0 epilogue (same block
// footprint); (3) gemmF stages B (HBM, slow) before A (L2, fast).
// gemmF core untouched (validated 2-buffer 2-phase, 2 blocks/CU).

constexpr int NN = 2048;
constexpr long GSTR = (long)NN * NN;
constexpr long SDN = 256L * 2048;   // [dout][n] plane stride

using frag8   = __attribute__((ext_vector_type(8))) short;   // 8 bf16
using floatx4 = __attribute__((ext_vector_type(4))) float;
using ush8    = __attribute__((ext_vector_type(8))) unsigned short;

__device__ inline unsigned short f2bf(float x) {
    unsigned u = __float_as_uint(x);
    u += 0x7FFF + ((u >> 16) & 1);   // RNE
    return (unsigned short)(u >> 16);
}
__device__ inline float bf2f(unsigned short h) {
    return __uint_as_float((unsigned)h << 16);
}
__device__ inline ushort2 pk2(float a, float b) {
    union { __hip_bfloat162 h; ushort2 u; } cv;
    cv.h = __float22bfloat162_rn(float2{a, b});
    return cv.u;
}
__device__ inline void gload_lds16(const void* g, void* l) {
    __builtin_amdgcn_global_load_lds(
        (const __attribute__((address_space(1))) void*)g,
        (__attribute__((address_space(3))) void*)l, 16, 0, 0);
}

// ---- flipped GEMM: CT[d][a] = sum_k A[d][k] * Bt[a][k]
// A row-major [256][2048] (L2-resident small matrix), Bt TILED [a>>7][k>>7][128][128].
// 512 blocks: bb = bx&7 (-> XCD, pins A panel in that XCD's L2), jt = 0..31, h = 0/1.
// 4 waves 2x2: wave = 128 d-rows x 32 a-cols; acc[8][2]; BK=64, pipelined dbuf.
// PHASE==1 h==0 blocks additionally emit out0 rows (folded out0k body).
template <int PHASE>   // 0 = GA, 1 = GB
__global__ __launch_bounds__(256) void gemmF(
    const unsigned short* __restrict__ Aa,   // GA: NeT ; GB: M1sT
    const unsigned short* __restrict__ Ab,   // GB: M2sT
    const unsigned short* __restrict__ Gb,   // Gbf tiled
    const unsigned short* __restrict__ GbT,  // GbfT tiled
    unsigned short* __restrict__ C0,         // GA: M1sT
    unsigned short* __restrict__ C1,         // GA: M2sT
    float* __restrict__ outp,                // GB
    const float* __restrict__ s0,            // GA: inv_rs ; GB: rs_raw
    const float* __restrict__ s1)            // GA: inv_cs ; GB: cs_raw
{
    constexpr int TM = 256, NT = 32;         // K=2048, BK=64
    __shared__ __align__(16) unsigned short SH[2][(TM + 64) * 64];  // 2x40KB

    const int bx = blockIdx.x;
    const int bb = bx & 7;
    const int rr_ = bx >> 3;                 // 0..63
    const int jt = rr_ & 31;
    const int h  = rr_ >> 5;                 // 0/1
    const int j0 = jt * 64;

    const unsigned short* Ap =
        ((PHASE == 1 && h) ? Ab : Aa) + (long)bb * SDN;
    const unsigned short* Bp =
        (((PHASE == 0) == (h == 0)) ? Gb : GbT) + (long)bb * GSTR;

    const int t = threadIdx.x;
    const int w = t >> 6, l = t & 63;
    const int wm = w >> 1, wn = w & 1;
    const int quad = l >> 4, c15 = l & 15;
    const int lr = l >> 3, ls = l & 7;

    floatx4 acc[8][2] = {};

    auto stage = [&](int buf, int k0) {
        // B first: HBM stream (~900cy) gets a head start over L2-served A (~200cy)
        const unsigned short* Bt = Bp + (((long)(j0 >> 7) * 16 + (k0 >> 7)) << 14);
        const int rb = j0 & 127, kin = k0 & 127;
        #pragma unroll
        for (int q = 0; q < 2; ++q) {        // B: 64 rows x 64 k from one tile
            const int rt = q * 32 + w * 8;
            gload_lds16(Bt + (rb + rt + lr) * 128 + kin + ((ls ^ lr) << 3),
                        &SH[buf][TM * 64 + rt * 64]);
        }
        #pragma unroll
        for (int q = 0; q < 8; ++q) {        // A: 256 rows x 64 k
            const int rt = q * 32 + w * 8;
            gload_lds16(Ap + (long)(rt + lr) * 2048 + k0 + ((ls ^ lr) << 3),
                        &SH[buf][rt * 64]);
        }
    };

    stage(0, 0);
    asm volatile("s_waitcnt vmcnt(0)" ::: "memory");
    __builtin_amdgcn_s_barrier();
    __builtin_amdgcn_sched_barrier(0);

    int cur = 0;
    for (int tt = 0; tt < NT; ++tt) {
        if (tt + 1 < NT) stage(cur ^ 1, (tt + 1) << 6);
        __builtin_amdgcn_sched_barrier(0);
        #pragma unroll
        for (int ks = 0; ks < 2; ++ks) {
            frag8 af[8], bfv[2];
            const int swr = c15 & 7;
            #pragma unroll
            for (int mt = 0; mt < 8; ++mt)
                af[mt] = *(const frag8*)&SH[cur][(wm * 128 + mt * 16 + c15) * 64
                                                + (((ks * 4 + quad) ^ swr) << 3)];
            #pragma unroll
            for (int nt = 0; nt < 2; ++nt)
                bfv[nt] = *(const frag8*)&SH[cur][TM * 64 + (wn * 32 + nt * 16 + c15) * 64
                                                 + (((ks * 4 + quad) ^ swr) << 3)];
            #pragma unroll
            for (int mt = 0; mt < 8; ++mt)
                #pragma unroll
                for (int nt = 0; nt < 2; ++nt)
                    acc[mt][nt] = __builtin_amdgcn_mfma_f32_16x16x32_bf16(
                        af[mt], bfv[nt], acc[mt][nt], 0, 0, 0);
        }
        if (tt + 1 < NT) {
            asm volatile("s_waitcnt vmcnt(0)" ::: "memory");
            __builtin_amdgcn_s_barrier();
            __builtin_amdgcn_sched_barrier(0);
        }
        cur ^= 1;
    }

    __syncthreads();   // K-loop LDS reads done; reuse SH for transpose epilogue

    // C/D frag layout: col(a) = lane&15, row(d) = quad*4 + e
    if constexpr (PHASE == 0) {
        // scale by column a, bf16, LDS-transpose, store rows of [256][2048]
        unsigned short* T16 = &SH[0][0];     // [256][72] (72*2B = 16-aligned rows)
        #pragma unroll
        for (int nt = 0; nt < 2; ++nt) {
            const int jc = wn * 32 + nt * 16 + c15;
            const float sc = (h ? s1 : s0)[(long)bb * 2048 + j0 + jc];
            #pragma unroll
            for (int mt = 0; mt < 8; ++mt) {
                const floatx4 v = acc[mt][nt];
                const int ib = wm * 128 + mt * 16 + quad * 4;
                #pragma unroll
                for (int e = 0; e < 4; ++e)
                    T16[(ib + e) * 72 + jc] = f2bf(v[e] * sc);
            }
        }
        __syncthreads();
        unsigned short* Co = (h ? C1 : C0) + ((long)bb * 256 + t) * 2048 + j0;
        const unsigned short* Tr = T16 + t * 72;
        #pragma unroll
        for (int c2 = 0; c2 < 8; ++c2)
            *(ush8*)(Co + c2 * 8) = *(const ush8*)(Tr + c2 * 8);
    } else {
        // relu, fp32 LDS-transpose, store 64 out-rows x 256 contiguous floats
        float* TF = (float*)&SH[0][0];       // [64][260] (260*4B = 16-aligned rows)
        #pragma unroll
        for (int nt = 0; nt < 2; ++nt) {
            const int jc = wn * 32 + nt * 16 + c15;
            #pragma unroll
            for (int mt = 0; mt < 8; ++mt) {
                const floatx4 v = acc[mt][nt];
                const int ib = wm * 128 + mt * 16 + quad * 4;
                #pragma unroll
                for (int e = 0; e < 4; ++e)
                    TF[jc * 260 + ib + e] = fmaxf(v[e], 0.f);
            }
        }
        __syncthreads();
        const int jr = t >> 2, iq = t & 3;
        float* Op = outp + ((long)bb * 2048 + j0 + jr) * 768 + (h ? 512 : 256) + iq * 64;
        const float* Sp = TF + jr * 260 + iq * 64;
        #pragma unroll
        for (int c2 = 0; c2 < 16; ++c2)
            *(float4*)(Op + c2 * 4) = *(const float4*)(Sp + c2 * 4);

        // ---- folded out0 (h==0 blocks only): same (bb, a-range) footprint.
        // out[a][0:256] = relu(0.5*(M1sT[d][a]*rs_raw[a] + M2sT[d][a]*cs_raw[a]))
        if (h == 0) {
            const int w0 = t >> 6, l0 = t & 63;
            const int rg0 = l0 >> 3, c0 = l0 & 7;
            const int ib0 = w0 * 64 + rg0 * 8;        // d base (8 rows)
            const int jb0 = j0 + c0 * 8;              // a base (8 cols)
            const long ab = (long)bb * SDN;

            union RowU { ush8 v; unsigned u4[4]; unsigned short a[8]; };
            RowU r1[8], r2[8], c1[8], c2v[8];
            #pragma unroll
            for (int r = 0; r < 8; ++r) {
                r1[r].v = *(const ush8*)(Aa + ab + (long)(ib0 + r) * 2048 + jb0);
                r2[r].v = *(const ush8*)(Ab + ab + (long)(ib0 + r) * 2048 + jb0);
            }
            #pragma unroll
            for (int p = 0; p < 4; ++p)
                #pragma unroll
                for (int k = 0; k < 4; ++k) {
                    const unsigned a1 = r1[2*p].u4[k], b1 = r1[2*p+1].u4[k];
                    c1[2*k].u4[p]   = (a1 & 0xffffu) | (b1 << 16);
                    c1[2*k+1].u4[p] = (a1 >> 16) | (b1 & 0xffff0000u);
                    const unsigned a2 = r2[2*p].u4[k], b2 = r2[2*p+1].u4[k];
                    c2v[2*k].u4[p]   = (a2 & 0xffffu) | (b2 << 16);
                    c2v[2*k+1].u4[p] = (a2 >> 16) | (b2 & 0xffff0000u);
                }
            #pragma unroll
            for (int jj = 0; jj < 8; ++jj) {
                const int j = jb0 + jj;
                const float rr = s0[(long)bb * 2048 + j];
                const float cc = s1[(long)bb * 2048 + j];
                float4 o0, o1;
                o0.x = fmaxf(0.5f * (bf2f(c1[jj].a[0]) * rr + bf2f(c2v[jj].a[0]) * cc), 0.f);
                o0.y = fmaxf(0.5f * (bf2f(c1[jj].a[1]) * rr + bf2f(c2v[jj].a[1]) * cc), 0.f);
                o0.z = fmaxf(0.5f * (bf2f(c1[jj].a[2]) * rr + bf2f(c2v[jj].a[2]) * cc), 0.f);
                o0.w = fmaxf(0.5f * (bf2f(c1[jj].a[3]) * rr + bf2f(c2v[jj].a[3]) * cc), 0.f);
                o1.x = fmaxf(0.5f * (bf2f(c1[jj].a[4]) * rr + bf2f(c2v[jj].a[4]) * cc), 0.f);
                o1.y = fmaxf(0.5f * (bf2f(c1[jj].a[5]) * rr + bf2f(c2v[jj].a[5]) * cc), 0.f);
                o1.z = fmaxf(0.5f * (bf2f(c1[jj].a[6]) * rr + bf2f(c2v[jj].a[6]) * cc), 0.f);
                o1.w = fmaxf(0.5f * (bf2f(c1[jj].a[7]) * rr + bf2f(c2v[jj].a[7]) * cc), 0.f);
                float* op = outp + ((long)bb * 2048 + j) * 768 + ib0;
                *(float4*)op       = o0;
                *(float4*)(op + 4) = o1;
            }
        }
    }
}

// ---- gemmNE: NeT[d][n] from H fp32 directly (R4-verified A_F32ROW path).
// C[i=n][j=d]: TM=64, WJ=64, grid 1024 = 32 i-tiles x 4 j x 8 b, XCD decode.
__global__ __launch_bounds__(256) void gemmNE(
    const float* __restrict__ H,               // [b][2048][256] fp32
    const unsigned short* __restrict__ Wt,     // [256][256] bf16 row-major
    unsigned short* __restrict__ NeT)          // [b][256][2048]
{
    constexpr int TM = 64, K = 256;
    __shared__ __align__(16) unsigned short As[TM * 64];
    __shared__ __align__(16) unsigned short Bs[64 * 64];

    const int t  = threadIdx.x;
    const int bx = blockIdx.x;
    const int xcd = bx & 7;
    const int kk  = bx >> 3;
    const int itile = xcd + 8 * (kk >> 5);     // PER = 32
    const int rem   = kk & 31;
    const int bb    = rem >> 2;
    const int jt    = rem & 3;
    const int i0b = itile * TM;
    const int j0  = jt * 64;

    const unsigned short* Btb = Wt + (long)j0 * K;
    const float* Af = H + (long)bb * (2048L * 256);

    const int w = t >> 6, l = t & 63;
    const int wm = w >> 1, wn = w & 1;
    const int quad = l >> 4, c15 = l & 15;
    const int lr = l >> 3, ls = l & 7;

    floatx4 acc[2][2] = {};

    for (int k0 = 0; k0 < K; k0 += 64) {
        // ---- stage A from fp32 (convert in registers)
        const int ar  = t >> 2;
        const int ac0 = (t & 3) * 2;
        const float* ap = Af + (long)(i0b + ar) * 256 + k0 + ac0 * 8;
        const float4 x0 = *(const float4*)(ap + 0);
        const float4 x1 = *(const float4*)(ap + 4);
        const float4 x2 = *(const float4*)(ap + 8);
        const float4 x3 = *(const float4*)(ap + 12);
        union { ush8 v; ushort2 u2[4]; } p0, p1;
        p0.u2[0] = pk2(x0.x, x0.y); p0.u2[1] = pk2(x0.z, x0.w);
        p0.u2[2] = pk2(x1.x, x1.y); p0.u2[3] = pk2(x1.z, x1.w);
        p1.u2[0] = pk2(x2.x, x2.y); p1.u2[1] = pk2(x2.z, x2.w);
        p1.u2[2] = pk2(x3.x, x3.y); p1.u2[3] = pk2(x3.z, x3.w);
        const int sw = ar & 7;
        *(ush8*)&As[ar * 64 + ((ac0 ^ sw) << 3)]       = p0.v;
        *(ush8*)&As[ar * 64 + (((ac0 + 1) ^ sw) << 3)] = p1.v;
        // ---- stage B (DMA)
        #pragma unroll
        for (int q = 0; q < 2; ++q) {
            const int rt = w * 16 + q * 8;
            gload_lds16(Btb + (long)(rt + lr) * K + k0 + ((ls ^ lr) << 3),
                        &Bs[rt * 64]);
        }
        __syncthreads();

        #pragma unroll
        for (int ks = 0; ks < 2; ++ks) {
            frag8 af[2], bfv[2];
            const int swr = c15 & 7;
            #pragma unroll
            for (int mt = 0; mt < 2; ++mt)
                af[mt] = *(const frag8*)&As[(wm * 32 + mt * 16 + c15) * 64
                                            + (((ks * 4 + quad) ^ swr) << 3)];
            #pragma unroll
            for (int nt = 0; nt < 2; ++nt)
                bfv[nt] = *(const frag8*)&Bs[(wn * 32 + nt * 16 + c15) * 64
                                             + (((ks * 4 + quad) ^ swr) << 3)];
            #pragma unroll
            for (int mt = 0; mt < 2; ++mt)
                #pragma unroll
                for (int nt = 0; nt < 2; ++nt)
                    acc[mt][nt] = __builtin_amdgcn_mfma_f32_16x16x32_bf16(
                        af[mt], bfv[nt], acc[mt][nt], 0, 0, 0);
        }
        __syncthreads();
    }

    #pragma unroll
    for (int mt = 0; mt < 2; ++mt) {
        const int ib = i0b + wm * 32 + mt * 16 + quad * 4;
        #pragma unroll
        for (int nt = 0; nt < 2; ++nt) {
            const floatx4 v = acc[mt][nt];
            const int gj = j0 + wn * 32 + nt * 16 + c15;
            union { ushort4 v; ushort2 u2[2]; } p;
            p.u2[0] = pk2(v[0], v[1]); p.u2[1] = pk2(v[2], v[3]);
            *(ushort4*)(NeT + ((long)bb * 256 + gj) * 2048 + ib) = p.v;
        }
    }
}

// ---- cvt_stream: G fp32 -> Gbf (tiled) + FULL row sums + col partials ----
__global__ __launch_bounds__(256) void cvt_stream(
    const float* __restrict__ G,
    unsigned short* __restrict__ Gbf,          // tiled [16][16][128][128]
    float* __restrict__ pcs,                   // [b][128][2048] col partials
    float* __restrict__ inv_rs, float* __restrict__ rs_raw)
{
    __shared__ float sm[4][16];
    const int b  = blockIdx.y;
    const int s  = blockIdx.x;                 // strip 0..127
    const int i0 = s * 16;
    const int t  = threadIdx.x;
    const int c8 = t * 8;
    const int w  = t >> 6, l = t & 63;

    const float* gp = G + (long)b * GSTR + (long)i0 * NN + c8;
    unsigned short* gb = Gbf + (long)b * GSTR;
    const int tc = c8 >> 7, cin = c8 & 127;

    float csum[8] = {};
    float rp[16];

    #pragma unroll
    for (int r = 0; r < 16; ++r) {
        const float4 x0 = *(const float4*)(gp + (long)r * NN);
        const float4 x1 = *(const float4*)(gp + (long)r * NN + 4);
        union { ush8 v; ushort2 u2[4]; } pk;
        pk.u2[0] = pk2(x0.x, x0.y); pk.u2[1] = pk2(x0.z, x0.w);
        pk.u2[2] = pk2(x1.x, x1.y); pk.u2[3] = pk2(x1.z, x1.w);
        const int gi = i0 + r;
        *(ush8*)(gb + (((long)(gi >> 7) * 16 + tc) << 14) + ((gi & 127) << 7) + cin) = pk.v;
        rp[r] = x0.x + x0.y + x0.z + x0.w + x1.x + x1.y + x1.z + x1.w;
        csum[0] += x0.x; csum[1] += x0.y; csum[2] += x0.z; csum[3] += x0.w;
        csum[4] += x1.x; csum[5] += x1.y; csum[6] += x1.z; csum[7] += x1.w;
    }

    float* pp = pcs + ((long)b * 128 + s) * NN + c8;
    *(float4*)pp       = make_float4(csum[0], csum[1], csum[2], csum[3]);
    *(float4*)(pp + 4) = make_float4(csum[4], csum[5], csum[6], csum[7]);

    #pragma unroll
    for (int r = 0; r < 16; ++r) {
        rp[r] += __shfl_xor(rp[r], 1);
        rp[r] += __shfl_xor(rp[r], 2);
        rp[r] += __shfl_xor(rp[r], 4);
        rp[r] += __shfl_xor(rp[r], 8);
        rp[r] += __shfl_xor(rp[r], 16);
        rp[r] += __shfl_xor(rp[r], 32);
    }
    if (l == 0) {
        #pragma unroll
        for (int r = 0; r < 16; ++r) sm[w][r] = rp[r];
    }
    __syncthreads();
    if (t < 16) {
        const float s_ = sm[0][t] + sm[1][t] + sm[2][t] + sm[3][t];
        rs_raw[(long)b * NN + i0 + t] = s_;
        inv_rs[(long)b * NN + i0 + t] = 1.0f / s_;
    }
}

// ---- cvt_t: tiled->tiled bf16 transpose. Block = one 128x128 tile.
__global__ __launch_bounds__(256) void cvt_t(
    const unsigned short* __restrict__ Gbf, unsigned short* __restrict__ GbfT)
{
    const int b  = blockIdx.z;
    const int tr = blockIdx.y, tc = blockIdx.x;
    const long src = (long)b * GSTR + (((long)tr * 16 + tc) << 14);
    const long dst = (long)b * GSTR + (((long)tc * 16 + tr) << 14);
    const int t = threadIdx.x;
    const int w = t >> 6, l = t & 63;
    const int wm = w >> 1, wn = w & 1;
    const int rg = l >> 3, c = l & 7;
    const int il = wm * 64 + rg * 8;
    const int jl = wn * 64 + c * 8;

    union RowU { ush8 v; unsigned u4[4]; };
    RowU rows[8], cols[8];
    #pragma unroll
    for (int r = 0; r < 8; ++r)
        rows[r].v = *(const ush8*)(Gbf + src + (long)(il + r) * 128 + jl);
    __builtin_amdgcn_sched_barrier(0);

    #pragma unroll
    for (int p = 0; p < 4; ++p)
        #pragma unroll
        for (int k = 0; k < 4; ++k) {
            const unsigned a = rows[2 * p].u4[k], bq = rows[2 * p + 1].u4[k];
            cols[2 * k].u4[p]     = (a & 0xffffu) | (bq << 16);
            cols[2 * k + 1].u4[p] = (a >> 16) | (bq & 0xffff0000u);
        }
    #pragma unroll
    for (int j = 0; j < 8; ++j)
        *(ush8*)(GbfT + dst + (long)(jl + j) * 128 + il) = cols[j].v;
}

// reduce col partials + W transpose: y=0 -> inv_cs+cs_raw ; y=1 -> Wt
__global__ __launch_bounds__(256) void finalize(
    const float* __restrict__ pcs,
    float* __restrict__ inv_cs, float* __restrict__ cs_raw,
    const float* __restrict__ W, unsigned short* __restrict__ Wt)
{
    const int idx = blockIdx.x * 256 + threadIdx.x;   // 0..16383
    if (blockIdx.y == 0) {
        const int b = idx >> 11, i = idx & 2047;
        float s = 0.f;
        for (int ic = 0; ic < 128; ++ic) s += pcs[((long)b * 128 + ic) * NN + i];
        inv_cs[idx] = 1.0f / s;
        cs_raw[idx] = s;
    } else {
        #pragma unroll
        for (int e = 0; e < 4; ++e) {
            const int flat = idx * 4 + e;              // 0..65535
            const int j = flat >> 8, k = flat & 255;
            Wt[flat] = f2bf(W[(long)k * 256 + j]);
        }
    }
}

extern "C" void kernel_launch(void* const* d_in, const int* in_sizes, int n_in,
                              void* d_out, int out_size, void* d_ws, size_t ws_size,
                              hipStream_t stream)
{
    constexpr int B = 8;
    const float* H = (const float*)d_in[0];
    const float* G = (const float*)d_in[1];
    const float* W = (const float*)d_in[2];
    float* out = (float*)d_out;

    unsigned short* ws16 = (unsigned short*)d_ws;
    unsigned short* Gbf  = ws16;                          // 33,554,432 shorts (tiled)
    unsigned short* GbfT = Gbf  + (long)B * GSTR;         // 33,554,432 (tiled)
    unsigned short* Wt   = GbfT + (long)B * GSTR;         // 65,536
    unsigned short* NeT  = Wt   + 65536;                  // 4,194,304 [b][256][2048]
    unsigned short* M1sT = NeT  + 4194304;                // 4,194,304
    unsigned short* M2sT = M1sT + 4194304;                // 4,194,304
    float* inv_rs = (float*)(M2sT + 4194304);             // 16384
    float* rs_raw = inv_rs + 16384;
    float* inv_cs = rs_raw + 16384;
    float* cs_raw = inv_cs + 16384;
    float* pcs    = cs_raw + 16384;                       // 8*128*2048 = 2M floats
    // total ~169 MB (ws = 512 MiB)

    cvt_stream<<<dim3(128, 8), 256, 0, stream>>>(G, Gbf, pcs, inv_rs, rs_raw);
    cvt_t<<<dim3(16, 16, 8), 256, 0, stream>>>(Gbf, GbfT);
    finalize<<<dim3(64, 2), 256, 0, stream>>>(pcs, inv_cs, cs_raw, W, Wt);

    // NeT = (H@W)^T directly from H fp32
    gemmNE<<<1024, 256, 0, stream>>>(H, Wt, NeT);
    // GA: M1sT (h=0, B=Gbf) + M2sT (h=1, B=GbfT), A=NeT L2-resident per XCD
    gemmF<0><<<512, 256, 0, stream>>>(NeT, nullptr, Gbf, GbfT,
                                      M1sT, M2sT, nullptr, inv_rs, inv_cs);
    // GB: out1 (h=0, A=M1sT, B=GbfT) + out2 (h=1, A=M2sT, B=Gbf) + folded out0
    gemmF<1><<<512, 256, 0, stream>>>(M1sT, M2sT, Gbf, GbfT,
                                      nullptr, nullptr, out, rs_raw, cs_raw);
}